// Round 6
// baseline (130.380 us; speedup 1.0000x reference)
//
#include <hip/hip_runtime.h>
#include <hip/hip_bf16.h>
#include <math.h>

typedef __bf16 bf16;
typedef __attribute__((ext_vector_type(8))) __bf16 bf16x8;
typedef __attribute__((ext_vector_type(4))) __bf16 bf16x4;
typedef __attribute__((ext_vector_type(2))) __bf16 bf16x2;
typedef __attribute__((ext_vector_type(4))) float f32x4;
typedef __attribute__((ext_vector_type(16))) float f32x16;
typedef __attribute__((ext_vector_type(4))) unsigned u32x4;

#define MFMA(a,b,c)   __builtin_amdgcn_mfma_f32_16x16x32_bf16(a,b,c,0,0,0)
#define MFMA32(a,b,c) __builtin_amdgcn_mfma_f32_32x32x16_bf16(a,b,c,0,0,0)

static constexpr int Bb = 4, Nn = 2048, Hh = 4;
// SS2 = SCALE^0.5 * sqrt(log2(e)) so that S' = S * log2(e); exp2(S') = e^S
static constexpr float SS2 = 0.4246609001440095f;

__device__ __forceinline__ void lds16(const bf16* src, bf16* dst) {
  __builtin_amdgcn_global_load_lds(
      (const __attribute__((address_space(1))) void*)src,
      (__attribute__((address_space(3))) void*)dst, 16, 0, 0);
}

__device__ __forceinline__ f32x16 zero16() {
  f32x16 t;
#pragma unroll
  for (int i = 0; i < 16; ++i) t[i] = 0.f;
  return t;
}

// ---------------- prep: weight transposes/casts + fold scaffolding + x->bf16 ----------------
// wqkv_t [512][256]: rows 0-255 Wqk^T, 256-511 Wv^T
// wout_b [384][256]: rows 0-255 Wout, row 256 bout, rows 257-383 zero (fold-GEMM A)
// wfold_t[512][512]: cols 0-255 = Wf1a^T (x-part); cols 256-511 written by fold GEMM
// wf1b_t [512][256]: Wf1b^T (fold-GEMM B operand)
// wf2_t  [256][512]: Wf2^T
__global__ __launch_bounds__(256) void prep_k(
    const float* Wqk, const float* Wv, const float* Wout, const float* bout,
    const float* Wf1, const float* Wf2, const float* x0, const float* x1,
    bf16* wqkv_t, bf16* wout_b, bf16* wfold_t, bf16* wf1b_t, bf16* wf2_t,
    bf16* xb0, bf16* xb1) {
  int id = blockIdx.x * 256 + threadIdx.x;
  if (id < 65536) { int k = id >> 8, n = id & 255; wqkv_t[n*256 + k] = (bf16)Wqk[id]; return; }
  id -= 65536;
  if (id < 65536) { int k = id >> 8, n = id & 255; wqkv_t[(256 + n)*256 + k] = (bf16)Wv[id]; return; }
  id -= 65536;
  if (id < 98304) {
    if (id < 65536) { wout_b[id] = (bf16)Wout[id]; }
    else { int id3 = id - 65536; int r = id3 >> 8, k = id3 & 255;
           wout_b[(256 + r)*256 + k] = (r == 0) ? (bf16)bout[k] : (bf16)0.f; }
    return; }
  id -= 98304;
  if (id < 131072) { int o = id & 511, k = id >> 9; wfold_t[o*512 + k] = (bf16)Wf1[k*512 + o]; return; }
  id -= 131072;
  if (id < 131072) { int o = id & 511, k = id >> 9; wf1b_t[o*256 + k] = (bf16)Wf1[(256 + k)*512 + o]; return; }
  id -= 131072;
  if (id < 131072) { int k = id >> 8, n = id & 255; wf2_t[n*512 + k] = (bf16)Wf2[id]; return; }
  id -= 131072;
  if (id < 1048576) {
    const float* xs = (id < 524288) ? x0 : x1;
    bf16* xd = (id < 524288) ? xb0 : xb1;
    int j = (id < 524288) ? id : id - 524288;
    f32x4 v = *reinterpret_cast<const f32x4*>(&xs[(size_t)j * 4]);
    bf16x4 o; o[0] = (bf16)v[0]; o[1] = (bf16)v[1]; o[2] = (bf16)v[2]; o[3] = (bf16)v[3];
    *reinterpret_cast<bf16x4*>(&xd[(size_t)j * 4]) = o;
  }
}

// ---------------- pipelined MFMA GEMM, 128xBN tile, BK=64, dbuf + lds16 ----------------
// MODE 5: A=xb, fused QK+V proj (N=512). cols<256 -> qks [B,H,N,64] (SS2, bqk);
//         cols>=256 -> vT [B,H,64,N] (bias bv via res).
// MODE 6: weight fold (N=512,K=256,M=384). A=wout_b, W=wf1b_t. rows<256 ->
//         wfold_t[cg][256+rg]; row 256 -> bfold[cg]=val+bf1[cg].
// MODE 3: A=xb|m (concat, K=512), out=acc+bfold -> hg bf16 [8192,512]
// MODE 4: A=hg (lda512), out=acc+bf2+xb(Ac) -> y f32 [8192,256]
template<int MODE, int BN, int MINW>
__global__ __launch_bounds__(256, MINW) void gemm_k(
    const bf16* Aa0, const bf16* Aa1, const bf16* Ac0, const bf16* Ac1,
    const bf16* Wt, const float* bias,
    bf16* ob0, bf16* ob1, float* of0, float* of1,
    const float* res0, const float* res1) {
  constexpr int KD  = (MODE == 3 || MODE == 4) ? 512 : 256;
  constexpr int LDA = (MODE == 4) ? 512 : 256;
  constexpr int NKC = KD / 64;
  constexpr int NF  = BN / 32;      // B-frags per wave; wave colspan = BN/2

  const int z = blockIdx.z;
  const bf16* Aa = z ? Aa1 : Aa0;
  const bf16* Ac = z ? Ac1 : Ac0;
  bf16*  ob = z ? ob1 : ob0;
  float* of = z ? of1 : of0;
  const float* res = z ? res1 : res0;

  const int tid = threadIdx.x;
  const int lane = tid & 63;
  const int w = tid >> 6;
  const int wr = w >> 1, wc = w & 1;
  const int m0r = blockIdx.x * 128;
  const int n0 = blockIdx.y * BN;
  const int r15 = lane & 15, g = lane >> 4, rb = r15 & 7;
  const int l3 = lane >> 3, l7 = lane & 7;
  const int swzc = (l7 ^ l3) * 8;

  __shared__ bf16 At[2][8192];
  __shared__ bf16 Bt[2][BN * 64];

  const bf16* aA = Aa + (size_t)(m0r + w*32 + l3) * LDA + swzc;
  const bf16* aC = (MODE == 3) ? (Ac + (size_t)(m0r + w*32 + l3) * 256 + swzc) : nullptr;
  const bf16* bB = Wt + (size_t)(n0 + w*(BN/4) + l3) * KD + swzc;
  const int adst = (w*32) * 64;
  const int bdst = (w*(BN/4)) * 64;

  auto stage = [&](int buf, int kc) {
    const bf16* ab; int kcol;
    if constexpr (MODE == 3) {
      if (kc < 4) { ab = aA; kcol = kc * 64; } else { ab = aC; kcol = (kc - 4) * 64; }
    } else { ab = aA; kcol = kc * 64; }
#pragma unroll
    for (int i = 0; i < 4; i++)
      lds16(ab + kcol + (size_t)i * 8 * LDA, &At[buf][adst + i*512]);
#pragma unroll
    for (int i = 0; i < NF; i++)
      lds16(bB + kc*64 + (size_t)i * 8 * KD, &Bt[buf][bdst + i*512]);
  };

  f32x4 acc[4][NF];
#pragma unroll
  for (int i = 0; i < 4; i++)
#pragma unroll
    for (int j = 0; j < NF; j++) acc[i][j] = f32x4{0.f, 0.f, 0.f, 0.f};

  const int rx0 = ((0*4 + g) ^ rb) << 4;
  const int rx1 = ((1*4 + g) ^ rb) << 4;

  auto compute = [&](int cur) {
    const char* Ap = (const char*)&At[cur][0];
    const char* Bp = (const char*)&Bt[cur][0];
    __builtin_amdgcn_s_setprio(1);
#pragma unroll
    for (int ks = 0; ks < 2; ++ks) {
      const int rx = ks ? rx1 : rx0;
      bf16x8 af[4], bfr[NF];
#pragma unroll
      for (int mf = 0; mf < 4; ++mf)
        af[mf] = *reinterpret_cast<const bf16x8*>(Ap + (wr*64 + mf*16 + r15) * 128 + rx);
#pragma unroll
      for (int nf = 0; nf < NF; ++nf)
        bfr[nf] = *reinterpret_cast<const bf16x8*>(Bp + (wc*(BN/2) + nf*16 + r15) * 128 + rx);
#pragma unroll
      for (int mf = 0; mf < 4; ++mf)
#pragma unroll
        for (int nf = 0; nf < NF; ++nf)
          acc[mf][nf] = MFMA(af[mf], bfr[nf], acc[mf][nf]);
    }
    __builtin_amdgcn_s_setprio(0);
  };

  stage(0, 0);
  int cur = 0;
  for (int kc = 0; kc < NKC - 1; ++kc) {
    stage(cur ^ 1, kc + 1);
    if constexpr (NF == 4) asm volatile("s_waitcnt vmcnt(8)" ::: "memory");
    else                   asm volatile("s_waitcnt vmcnt(6)" ::: "memory");
    __builtin_amdgcn_sched_barrier(0);
    __builtin_amdgcn_s_barrier();
    __builtin_amdgcn_sched_barrier(0);
    compute(cur);
    asm volatile("s_waitcnt lgkmcnt(0)" ::: "memory");
    __builtin_amdgcn_sched_barrier(0);
    __builtin_amdgcn_s_barrier();
    __builtin_amdgcn_sched_barrier(0);
    cur ^= 1;
  }
  asm volatile("s_waitcnt vmcnt(0)" ::: "memory");
  __builtin_amdgcn_sched_barrier(0);
  __builtin_amdgcn_s_barrier();
  __builtin_amdgcn_sched_barrier(0);
  compute(cur);

  // ---- epilogue ----
#pragma unroll
  for (int mf = 0; mf < 4; ++mf)
#pragma unroll
    for (int nf = 0; nf < NF; ++nf) {
      f32x4 c = acc[mf][nf];
      int cg = n0 + wc*(BN/2) + nf*16 + r15;
#pragma unroll
      for (int r = 0; r < 4; ++r) {
        int rg = m0r + wr*64 + mf*16 + g*4 + r;
        if constexpr (MODE == 5) {
          int b = rg >> 11, n = rg & 2047;
          if (cg < 256) {
            float val = (c[r] + bias[cg]) * SS2;
            int h = cg >> 6, dh = cg & 63;
            ob[(((size_t)(b*Hh + h)) * Nn + n) * 64 + dh] = (bf16)val;
          } else {
            int c2 = cg - 256;
            float val = c[r] + res[c2];            // res carries bv
            int h = c2 >> 6, dh = c2 & 63;
            ((bf16*)of)[(((size_t)(b*Hh + h)) * 64 + dh) * Nn + n] = (bf16)val;
          }
        } else if constexpr (MODE == 6) {
          if (rg < 256) ob[(size_t)cg * 512 + 256 + rg] = (bf16)c[r];
          else if (rg == 256) of[cg] = c[r] + bias[cg];   // bias = bf1
        } else if constexpr (MODE == 3) {
          ob[(size_t)rg * 512 + cg] = (bf16)(c[r] + bias[cg]);
        } else {   // MODE 4
          of[(size_t)rg * 256 + cg] = c[r] + bias[cg] + (float)Ac[(size_t)rg * 256 + cg];
        }
      }
    }
}

// ---------------- fused dual-direction attention: 32x32 MFMA, in-register P,
// quad-buffered K/V, ONE barrier per j-tile, VALU rowsum ----------------
__global__ __launch_bounds__(256, 2) void attn_k(
    const bf16* qks0, const bf16* qks1, const bf16* vT0, const bf16* vT1,
    bf16* m0o, bf16* m1o) {
  const int B = blockIdx.x + 16 * (blockIdx.y + 16 * blockIdx.z);
  const int xcd = B & 7, kk = B >> 3;          // kk 0..63
  const int group = 4 * xcd + (kk >> 4);       // 0..31 = dir*16 + bh
  const int it = kk & 15;
  const int bh = group & 15, dir = group >> 4;

  const bf16* Q  = (dir ? qks1 : qks0) + (size_t)bh * (Nn * 64);
  const bf16* Kp = (dir ? qks0 : qks1) + (size_t)bh * (Nn * 64);
  const bf16* Vp = (dir ? vT0  : vT1 ) + (size_t)bh * (64 * Nn);
  bf16* out = dir ? m1o : m0o;
  const int b = bh >> 2, h = bh & 3;

  const int tid = threadIdx.x, lane = tid & 63, w = tid >> 6;
  const int l31 = lane & 31, hi = lane >> 5, xr = l31 & 7;
  const int iw = it * 128 + w * 32;            // wave's first q-row

  __shared__ bf16 Kt[4][4096];                 // [buf][64 j x 64 d], swizzled
  __shared__ bf16 Vt[4][4096];                 // [buf][64 d x 64 j], swizzled
  __shared__ float Rt[4][32];                  // per-wave rowsum redistribute

  // ---- Q fragments (B-operand: col i = l31, k d = kt*16 + hi*8 + e) ----
  bf16x8 qf[4];
#pragma unroll
  for (int kt = 0; kt < 4; ++kt)
    qf[kt] = *reinterpret_cast<const bf16x8*>(
        &Q[(size_t)(iw + l31) * 64 + kt*16 + hi*8]);

  f32x16 acc[2]; acc[0] = zero16(); acc[1] = zero16();
  float rsum = 0.f;   // Sigma_j E for (i=l31, this hi's j-subset)

  // ---- staging (pre-swizzled global sources, linear LDS dests) ----
  const int l3 = lane >> 3, l7 = lane & 7;
  const int swz = ((l7 ^ l3) * 8);
  const bf16* ks0 = Kp + (size_t)(w*16 +     l3) * 64 + swz;
  const bf16* ks1 = Kp + (size_t)(w*16 + 8 + l3) * 64 + swz;
  const bf16* vs0 = Vp + (size_t)(w*16 +     l3) * 2048 + swz;
  const bf16* vs1 = Vp + (size_t)(w*16 + 8 + l3) * 2048 + swz;
  const int kd0 = (w*16    ) * 64;
  const int kd1 = (w*16 + 8) * 64;

  auto stage = [&](int buf, int j0) {
    lds16(ks0 + (size_t)j0 * 64, &Kt[buf][kd0]);
    lds16(ks1 + (size_t)j0 * 64, &Kt[buf][kd1]);
    lds16(vs0 + j0,              &Vt[buf][kd0]);
    lds16(vs1 + j0,              &Vt[buf][kd1]);
  };

  // read-offset tables (bytes)
  int kby[2][4], vby[2][4];
#pragma unroll
  for (int jm = 0; jm < 2; ++jm)
#pragma unroll
    for (int kt = 0; kt < 4; ++kt)
      kby[jm][kt] = (jm*32 + l31) * 128 + (((2*kt + hi) ^ xr) << 4);
#pragma unroll
  for (int nt = 0; nt < 2; ++nt)
#pragma unroll
    for (int gg = 0; gg < 4; ++gg)
      vby[nt][gg] = (nt*32 + l31) * 128 + (((2*gg + hi) ^ xr) << 4);

  auto compute_tile = [&](int cur) {
    const char* Kb = (const char*)&Kt[cur][0];
    const char* Vb = (const char*)&Vt[cur][0];
    // --- QK^T: S^T[j][i], col i = l31, rows j from reg layout ---
    f32x16 st[2];
    __builtin_amdgcn_s_setprio(1);
#pragma unroll
    for (int jm = 0; jm < 2; ++jm) {
      f32x16 t = zero16();
#pragma unroll
      for (int kt = 0; kt < 4; ++kt) {
        bf16x8 kf = *reinterpret_cast<const bf16x8*>(Kb + kby[jm][kt]);
        t = MFMA32(kf, qf[kt], t);
      }
      st[jm] = t;
    }
    __builtin_amdgcn_s_setprio(0);
    // --- exp2 + VALU rowsum + bf16x2 pack + permlane32_swap -> PA in-register ---
    bf16x8 pa[4];
#pragma unroll
    for (int jm = 0; jm < 2; ++jm) {
      unsigned dw[8];
#pragma unroll
      for (int s = 0; s < 8; ++s) {
        float e0 = __builtin_amdgcn_exp2f(st[jm][2*s]);
        float e1 = __builtin_amdgcn_exp2f(st[jm][2*s + 1]);
        rsum += e0 + e1;
        bf16x2 p; p[0] = (bf16)e0; p[1] = (bf16)e1;
        dw[s] = __builtin_bit_cast(unsigned, p);
      }
#pragma unroll
      for (int kt2 = 0; kt2 < 2; ++kt2) {
        unsigned a0 = dw[4*kt2 + 0], b0 = dw[4*kt2 + 2];
        unsigned a1 = dw[4*kt2 + 1], b1 = dw[4*kt2 + 3];
        asm volatile("v_permlane32_swap_b32 %0, %1" : "+v"(a0), "+v"(b0));
        asm volatile("v_permlane32_swap_b32 %0, %1" : "+v"(a1), "+v"(b1));
        u32x4 uu; uu[0] = a0; uu[1] = a1; uu[2] = b0; uu[3] = b1;
        pa[jm*2 + kt2] = __builtin_bit_cast(bf16x8, uu);
      }
    }
    // --- PV (A = PA rows i, k = j) ---
    __builtin_amdgcn_s_setprio(1);
#pragma unroll
    for (int gg = 0; gg < 4; ++gg) {
#pragma unroll
      for (int nt = 0; nt < 2; ++nt) {
        bf16x8 vf = *reinterpret_cast<const bf16x8*>(Vb + vby[nt][gg]);
        acc[nt] = MFMA32(pa[gg], vf, acc[nt]);
      }
    }
    __builtin_amdgcn_s_setprio(0);
  };

  // ---- quad-buffered main loop: ONE barrier per tile ----
  stage(0, 0); stage(1, 1 << 6); stage(2, 2 << 6);
  for (int jt = 0; jt < 30; ++jt) {
    asm volatile("s_waitcnt vmcnt(8)" ::: "memory");
    __builtin_amdgcn_sched_barrier(0);
    __builtin_amdgcn_s_barrier();
    __builtin_amdgcn_sched_barrier(0);
    stage((jt + 3) & 3, (jt + 3) << 6);   // overwrites buf of tile jt-1 (all done)
    compute_tile(jt & 3);
  }
  asm volatile("s_waitcnt vmcnt(4)" ::: "memory");
  __builtin_amdgcn_sched_barrier(0);
  __builtin_amdgcn_s_barrier();
  __builtin_amdgcn_sched_barrier(0);
  compute_tile(2);
  asm volatile("s_waitcnt vmcnt(0)" ::: "memory");
  __builtin_amdgcn_sched_barrier(0);
  __builtin_amdgcn_s_barrier();
  __builtin_amdgcn_sched_barrier(0);
  compute_tile(3);

  // ---- epilogue: complete rowsum, redistribute to acc rows, divide, write ----
  rsum += __shfl_xor(rsum, 32);            // both hi halves hold full rowsum[i=l31]
  if (lane < 32) Rt[w][l31] = rsum;        // wave-internal; lgkm ordering suffices
  f32x4 rv[4];
#pragma unroll
  for (int q = 0; q < 4; ++q)
    rv[q] = *reinterpret_cast<const f32x4*>(&Rt[w][8*q + 4*hi]);
#pragma unroll
  for (int r = 0; r < 16; ++r) {
    float inv = 1.0f / rv[r >> 2][r & 3];
    int row = iw + (r & 3) + 8*(r >> 2) + 4*hi;
#pragma unroll
    for (int nt = 0; nt < 2; ++nt) {
      int col = h*64 + nt*32 + l31;
      out[((size_t)b * Nn + row) * 256 + col] = (bf16)(acc[nt][r] * inv);
    }
  }
}

// ---------------- LayerNorm + exact GELU: one wave per 512-col row ----------------
__global__ __launch_bounds__(256) void ln_gelu_k(
    bf16* hg, const float* g, const float* bb) {
  const int row = (blockIdx.x << 2) + (threadIdx.x >> 6);
  const int lane = threadIdx.x & 63;
  bf16* hr = hg + (size_t)row * 512 + lane * 8;
  bf16x8 v = *reinterpret_cast<const bf16x8*>(hr);
  float f[8];
  float s = 0.f, sq = 0.f;
#pragma unroll
  for (int i = 0; i < 8; ++i) { f[i] = (float)v[i]; s += f[i]; sq += f[i]*f[i]; }
#pragma unroll
  for (int m = 1; m < 64; m <<= 1) { s += __shfl_xor(s, m); sq += __shfl_xor(sq, m); }
  float mu = s * (1.f / 512.f);
  float var = sq * (1.f / 512.f) - mu * mu;
  float rsv = rsqrtf(var + 1e-5f);
  f32x4 g0 = *reinterpret_cast<const f32x4*>(&g[lane*8]);
  f32x4 g1 = *reinterpret_cast<const f32x4*>(&g[lane*8 + 4]);
  f32x4 b0 = *reinterpret_cast<const f32x4*>(&bb[lane*8]);
  f32x4 b1 = *reinterpret_cast<const f32x4*>(&bb[lane*8 + 4]);
  bf16x8 o;
#pragma unroll
  for (int i = 0; i < 8; ++i) {
    float gv = (i < 4) ? g0[i] : g1[i-4];
    float bv = (i < 4) ? b0[i] : b1[i-4];
    float xn = (f[i] - mu) * rsv * gv + bv;
    float ge = 0.5f * xn * (1.f + erff(xn * 0.70710678118f));
    o[i] = (bf16)ge;
  }
  *reinterpret_cast<bf16x8*>(hr) = o;
}

extern "C" void kernel_launch(void* const* d_in, const int* in_sizes, int n_in,
                              void* d_out, int out_size, void* d_ws, size_t ws_size,
                              hipStream_t stream) {
  (void)in_sizes; (void)n_in; (void)out_size; (void)ws_size;
  const float* x0   = (const float*)d_in[0];
  const float* x1   = (const float*)d_in[1];
  const float* Wqk  = (const float*)d_in[2];
  const float* bqk  = (const float*)d_in[3];
  const float* Wv   = (const float*)d_in[4];
  const float* bv   = (const float*)d_in[5];
  const float* Wout = (const float*)d_in[6];
  const float* bout = (const float*)d_in[7];
  const float* Wf1  = (const float*)d_in[8];
  const float* bf1  = (const float*)d_in[9];
  const float* ln_g = (const float*)d_in[10];
  const float* ln_b = (const float*)d_in[11];
  const float* Wf2  = (const float*)d_in[12];
  const float* bf2  = (const float*)d_in[13];
  float* y = (float*)d_out;

  bf16* p = (bf16*)d_ws;
  bf16* wqkv_t = p; p += 131072;
  bf16* wout_b = p; p += 98304;
  bf16* wfold_t = p; p += 262144;
  bf16* wf1b_t = p; p += 131072;
  bf16* wf2_t  = p; p += 131072;
  float* bfold = (float*)p; p += 1024;     // 512 f32
  bf16* xb0  = p; p += 2097152;
  bf16* xb1  = p; p += 2097152;
  bf16* qks0 = p; p += 2097152;
  bf16* qks1 = p; p += 2097152;
  bf16* vT0  = p; p += 2097152;
  bf16* vT1  = p; p += 2097152;
  bf16* m0   = p; p += 2097152;
  bf16* m1   = p; p += 2097152;
  bf16* hg0  = p; p += 4194304;
  bf16* hg1  = p; p += 4194304;

  dim3 blk(256);
  prep_k<<<6528, blk, 0, stream>>>(Wqk, Wv, Wout, bout, Wf1, Wf2, x0, x1,
                                   wqkv_t, wout_b, wfold_t, wf1b_t, wf2_t, xb0, xb1);
  // weight fold: Wc = [Wout; bout] @ Wf1b  -> wfold_t cols 256-511, bfold
  gemm_k<6,128,2><<<dim3(3, 4, 1), blk, 0, stream>>>(
      wout_b, wout_b, nullptr, nullptr, wf1b_t, bf1,
      wfold_t, wfold_t, bfold, bfold, nullptr, nullptr);
  gemm_k<5,128,2><<<dim3(64, 4, 2), blk, 0, stream>>>(
      xb0, xb1, nullptr, nullptr, wqkv_t, bqk,
      qks0, qks1, (float*)vT0, (float*)vT1, bv, bv);
  attn_k<<<dim3(16, 16, 2), blk, 0, stream>>>(qks0, qks1, vT0, vT1, m0, m1);
  gemm_k<3,128,2><<<dim3(64, 4, 2), blk, 0, stream>>>(
      xb0, xb1, m0, m1, wfold_t, bfold,
      hg0, hg1, nullptr, nullptr, nullptr, nullptr);
  ln_gelu_k<<<dim3(4096), blk, 0, stream>>>(hg0, ln_g, ln_b);
  gemm_k<4,64,3><<<dim3(64, 4, 2), blk, 0, stream>>>(
      hg0, hg1, xb0, xb1, wf2_t, bf2,
      nullptr, nullptr, y, y + 2097152, nullptr, nullptr);
}

// Round 7
// 129.789 us; speedup vs baseline: 1.0046x; 1.0046x over previous
//
#include <hip/hip_runtime.h>
#include <hip/hip_bf16.h>
#include <math.h>

typedef __bf16 bf16;
typedef __attribute__((ext_vector_type(8))) __bf16 bf16x8;
typedef __attribute__((ext_vector_type(4))) __bf16 bf16x4;
typedef __attribute__((ext_vector_type(2))) __bf16 bf16x2;
typedef __attribute__((ext_vector_type(4))) float f32x4;
typedef __attribute__((ext_vector_type(16))) float f32x16;
typedef __attribute__((ext_vector_type(4))) unsigned u32x4;

#define MFMA(a,b,c)   __builtin_amdgcn_mfma_f32_16x16x32_bf16(a,b,c,0,0,0)
#define MFMA32(a,b,c) __builtin_amdgcn_mfma_f32_32x32x16_bf16(a,b,c,0,0,0)

static constexpr int Bb = 4, Nn = 2048, Hh = 4;
// SS2 = SCALE^0.5 * sqrt(log2(e)) so that S' = S * log2(e); exp2(S') = e^S
static constexpr float SS2 = 0.4246609001440095f;

__device__ __forceinline__ void lds16(const bf16* src, bf16* dst) {
  __builtin_amdgcn_global_load_lds(
      (const __attribute__((address_space(1))) void*)src,
      (__attribute__((address_space(3))) void*)dst, 16, 0, 0);
}

__device__ __forceinline__ f32x16 zero16() {
  f32x16 t;
#pragma unroll
  for (int i = 0; i < 16; ++i) t[i] = 0.f;
  return t;
}

// ---------------- prep: weight transposes/casts + fold scaffolding + x->bf16 ----------------
__global__ __launch_bounds__(256) void prep_k(
    const float* Wqk, const float* Wv, const float* Wout, const float* bout,
    const float* Wf1, const float* Wf2, const float* x0, const float* x1,
    bf16* wqkv_t, bf16* wout_b, bf16* wfold_t, bf16* wf1b_t, bf16* wf2_t,
    bf16* xb0, bf16* xb1) {
  int id = blockIdx.x * 256 + threadIdx.x;
  if (id < 65536) { int k = id >> 8, n = id & 255; wqkv_t[n*256 + k] = (bf16)Wqk[id]; return; }
  id -= 65536;
  if (id < 65536) { int k = id >> 8, n = id & 255; wqkv_t[(256 + n)*256 + k] = (bf16)Wv[id]; return; }
  id -= 65536;
  if (id < 98304) {
    if (id < 65536) { wout_b[id] = (bf16)Wout[id]; }
    else { int id3 = id - 65536; int r = id3 >> 8, k = id3 & 255;
           wout_b[(256 + r)*256 + k] = (r == 0) ? (bf16)bout[k] : (bf16)0.f; }
    return; }
  id -= 98304;
  if (id < 131072) { int o = id & 511, k = id >> 9; wfold_t[o*512 + k] = (bf16)Wf1[k*512 + o]; return; }
  id -= 131072;
  if (id < 131072) { int o = id & 511, k = id >> 9; wf1b_t[o*256 + k] = (bf16)Wf1[(256 + k)*512 + o]; return; }
  id -= 131072;
  if (id < 131072) { int k = id >> 8, n = id & 255; wf2_t[n*512 + k] = (bf16)Wf2[id]; return; }
  id -= 131072;
  if (id < 1048576) {
    const float* xs = (id < 524288) ? x0 : x1;
    bf16* xd = (id < 524288) ? xb0 : xb1;
    int j = (id < 524288) ? id : id - 524288;
    f32x4 v = *reinterpret_cast<const f32x4*>(&xs[(size_t)j * 4]);
    bf16x4 o; o[0] = (bf16)v[0]; o[1] = (bf16)v[1]; o[2] = (bf16)v[2]; o[3] = (bf16)v[3];
    *reinterpret_cast<bf16x4*>(&xd[(size_t)j * 4]) = o;
  }
}

// ---------------- pipelined MFMA GEMM, 128xBN tile, BK=64, dbuf + lds16 ----------------
// MODE 5: A=xb, fused QK+V proj (N=512). cols<256 -> qks (SS2, bqk);
//         cols>=256 -> vT (bias bv via res).
// MODE 6: weight fold (N=512,K=256,M=384). rows<256 -> wfold_t[cg][256+rg];
//         row 256 -> bfold[cg]=val+bf1[cg].
// MODE 3: A=xb|m (concat, K=512), out=acc+bfold -> hg bf16 [8192,512]
// MODE 4: A=hg (lda512), out=acc+bf2+xb(Ac) -> y f32 [8192,256]
// REMAP=1: XCD-bijective blockIdx swizzle for 512-block grids (64,4,2) so all
// 4 n-blocks of one m-panel share an XCD's L2 (A fetched once from HBM).
template<int MODE, int BN, int MINW, int REMAP>
__global__ __launch_bounds__(256, MINW) void gemm_k(
    const bf16* Aa0, const bf16* Aa1, const bf16* Ac0, const bf16* Ac1,
    const bf16* Wt, const float* bias,
    bf16* ob0, bf16* ob1, float* of0, float* of1,
    const float* res0, const float* res1) {
  constexpr int KD  = (MODE == 3 || MODE == 4) ? 512 : 256;
  constexpr int LDA = (MODE == 4) ? 512 : 256;
  constexpr int NKC = KD / 64;
  constexpr int NF  = BN / 32;      // B-frags per wave; wave colspan = BN/2

  int bx = blockIdx.x, by = blockIdx.y, bz = blockIdx.z;
  if constexpr (REMAP) {
    int id = blockIdx.x + 64 * (blockIdx.y + 4 * blockIdx.z);
    bx = ((id & 7) << 3) + ((id >> 3) & 7);
    by = (id >> 6) & 3;
    bz = id >> 8;
  }

  const bf16* Aa = bz ? Aa1 : Aa0;
  const bf16* Ac = bz ? Ac1 : Ac0;
  bf16*  ob = bz ? ob1 : ob0;
  float* of = bz ? of1 : of0;
  const float* res = bz ? res1 : res0;

  const int tid = threadIdx.x;
  const int lane = tid & 63;
  const int w = tid >> 6;
  const int wr = w >> 1, wc = w & 1;
  const int m0r = bx * 128;
  const int n0 = by * BN;
  const int r15 = lane & 15, g = lane >> 4, rb = r15 & 7;
  const int l3 = lane >> 3, l7 = lane & 7;
  const int swzc = (l7 ^ l3) * 8;

  __shared__ bf16 At[2][8192];
  __shared__ bf16 Bt[2][BN * 64];

  const bf16* aA = Aa + (size_t)(m0r + w*32 + l3) * LDA + swzc;
  const bf16* aC = (MODE == 3) ? (Ac + (size_t)(m0r + w*32 + l3) * 256 + swzc) : nullptr;
  const bf16* bB = Wt + (size_t)(n0 + w*(BN/4) + l3) * KD + swzc;
  const int adst = (w*32) * 64;
  const int bdst = (w*(BN/4)) * 64;

  auto stage = [&](int buf, int kc) {
    const bf16* ab; int kcol;
    if constexpr (MODE == 3) {
      if (kc < 4) { ab = aA; kcol = kc * 64; } else { ab = aC; kcol = (kc - 4) * 64; }
    } else { ab = aA; kcol = kc * 64; }
#pragma unroll
    for (int i = 0; i < 4; i++)
      lds16(ab + kcol + (size_t)i * 8 * LDA, &At[buf][adst + i*512]);
#pragma unroll
    for (int i = 0; i < NF; i++)
      lds16(bB + kc*64 + (size_t)i * 8 * KD, &Bt[buf][bdst + i*512]);
  };

  f32x4 acc[4][NF];
#pragma unroll
  for (int i = 0; i < 4; i++)
#pragma unroll
    for (int j = 0; j < NF; j++) acc[i][j] = f32x4{0.f, 0.f, 0.f, 0.f};

  const int rx0 = ((0*4 + g) ^ rb) << 4;
  const int rx1 = ((1*4 + g) ^ rb) << 4;

  auto compute = [&](int cur) {
    const char* Ap = (const char*)&At[cur][0];
    const char* Bp = (const char*)&Bt[cur][0];
    __builtin_amdgcn_s_setprio(1);
#pragma unroll
    for (int ks = 0; ks < 2; ++ks) {
      const int rx = ks ? rx1 : rx0;
      bf16x8 af[4], bfr[NF];
#pragma unroll
      for (int mf = 0; mf < 4; ++mf)
        af[mf] = *reinterpret_cast<const bf16x8*>(Ap + (wr*64 + mf*16 + r15) * 128 + rx);
#pragma unroll
      for (int nf = 0; nf < NF; ++nf)
        bfr[nf] = *reinterpret_cast<const bf16x8*>(Bp + (wc*(BN/2) + nf*16 + r15) * 128 + rx);
#pragma unroll
      for (int mf = 0; mf < 4; ++mf)
#pragma unroll
        for (int nf = 0; nf < NF; ++nf)
          acc[mf][nf] = MFMA(af[mf], bfr[nf], acc[mf][nf]);
    }
    __builtin_amdgcn_s_setprio(0);
  };

  stage(0, 0);
  int cur = 0;
  for (int kc = 0; kc < NKC - 1; ++kc) {
    stage(cur ^ 1, kc + 1);
    if constexpr (NF == 4) asm volatile("s_waitcnt vmcnt(8)" ::: "memory");
    else                   asm volatile("s_waitcnt vmcnt(6)" ::: "memory");
    __builtin_amdgcn_sched_barrier(0);
    __builtin_amdgcn_s_barrier();
    __builtin_amdgcn_sched_barrier(0);
    compute(cur);
    asm volatile("s_waitcnt lgkmcnt(0)" ::: "memory");
    __builtin_amdgcn_sched_barrier(0);
    __builtin_amdgcn_s_barrier();
    __builtin_amdgcn_sched_barrier(0);
    cur ^= 1;
  }
  asm volatile("s_waitcnt vmcnt(0)" ::: "memory");
  __builtin_amdgcn_sched_barrier(0);
  __builtin_amdgcn_s_barrier();
  __builtin_amdgcn_sched_barrier(0);
  compute(cur);

  // ---- epilogue ----
#pragma unroll
  for (int mf = 0; mf < 4; ++mf)
#pragma unroll
    for (int nf = 0; nf < NF; ++nf) {
      f32x4 c = acc[mf][nf];
      int cg = n0 + wc*(BN/2) + nf*16 + r15;
#pragma unroll
      for (int r = 0; r < 4; ++r) {
        int rg = m0r + wr*64 + mf*16 + g*4 + r;
        if constexpr (MODE == 5) {
          int b = rg >> 11, n = rg & 2047;
          if (cg < 256) {
            float val = (c[r] + bias[cg]) * SS2;
            int h = cg >> 6, dh = cg & 63;
            ob[(((size_t)(b*Hh + h)) * Nn + n) * 64 + dh] = (bf16)val;
          } else {
            int c2 = cg - 256;
            float val = c[r] + res[c2];            // res carries bv
            int h = c2 >> 6, dh = c2 & 63;
            ((bf16*)of)[(((size_t)(b*Hh + h)) * 64 + dh) * Nn + n] = (bf16)val;
          }
        } else if constexpr (MODE == 6) {
          if (rg < 256) ob[(size_t)cg * 512 + 256 + rg] = (bf16)c[r];
          else if (rg == 256) of[cg] = c[r] + bias[cg];   // bias = bf1
        } else if constexpr (MODE == 3) {
          ob[(size_t)rg * 512 + cg] = (bf16)(c[r] + bias[cg]);
        } else {   // MODE 4
          of[(size_t)rg * 256 + cg] = c[r] + bias[cg] + (float)Ac[(size_t)rg * 256 + cg];
        }
      }
    }
}

// ---------------- fused dual-direction attention, 32x32 MFMA, in-register P ----------------
// Round-5 structure (best measured): 128 i-rows/block (4 waves x 32), j-tile 64,
// double-buffered K/V via global_load_lds + counted vmcnt + raw barriers,
// XOR-swizzled LDS, S^T = mfma32(K,Q), P in registers via exp2 +
// v_cvt_pk_bf16_f32 + permlane32_swap, rowsum via mfma32(P, ones).
__global__ __launch_bounds__(256, 2) void attn_k(
    const bf16* qks0, const bf16* qks1, const bf16* vT0, const bf16* vT1,
    bf16* m0o, bf16* m1o) {
  const int B = blockIdx.x + 16 * (blockIdx.y + 16 * blockIdx.z);
  const int xcd = B & 7, kk = B >> 3;          // kk 0..63
  const int group = 4 * xcd + (kk >> 4);       // 0..31 = dir*16 + bh
  const int it = kk & 15;
  const int bh = group & 15, dir = group >> 4;

  const bf16* Q  = (dir ? qks1 : qks0) + (size_t)bh * (Nn * 64);
  const bf16* Kp = (dir ? qks0 : qks1) + (size_t)bh * (Nn * 64);
  const bf16* Vp = (dir ? vT0  : vT1 ) + (size_t)bh * (64 * Nn);
  bf16* out = dir ? m1o : m0o;
  const int b = bh >> 2, h = bh & 3;

  const int tid = threadIdx.x, lane = tid & 63, w = tid >> 6;
  const int l31 = lane & 31, hi = lane >> 5, xr = l31 & 7;
  const int iw = it * 128 + w * 32;            // wave's first q-row

  __shared__ bf16 Kt[2][4096];                 // [buf][64 j x 64 d], swizzled
  __shared__ bf16 Vt[2][4096];                 // [buf][64 d x 64 j], swizzled

  // ---- Q fragments (B-operand: col i = l31, k d = kt*16 + hi*8 + e) ----
  bf16x8 qf[4];
#pragma unroll
  for (int kt = 0; kt < 4; ++kt)
    qf[kt] = *reinterpret_cast<const bf16x8*>(
        &Q[(size_t)(iw + l31) * 64 + kt*16 + hi*8]);

  bf16x8 ones;
#pragma unroll
  for (int i = 0; i < 8; ++i) ones[i] = (bf16)1.0f;

  f32x16 acc[2]; acc[0] = zero16(); acc[1] = zero16();
  f32x16 rsacc = zero16();

  // ---- staging (pre-swizzled global sources, linear LDS dests) ----
  const int l3 = lane >> 3, l7 = lane & 7;
  const int swz = ((l7 ^ l3) * 8);
  const bf16* ks0 = Kp + (size_t)(w*16 +     l3) * 64 + swz;
  const bf16* ks1 = Kp + (size_t)(w*16 + 8 + l3) * 64 + swz;
  const bf16* vs0 = Vp + (size_t)(w*16 +     l3) * 2048 + swz;
  const bf16* vs1 = Vp + (size_t)(w*16 + 8 + l3) * 2048 + swz;
  const int kd0 = (w*16    ) * 64;
  const int kd1 = (w*16 + 8) * 64;

  auto stage = [&](int buf, int j0) {
    lds16(ks0 + (size_t)j0 * 64, &Kt[buf][kd0]);
    lds16(ks1 + (size_t)j0 * 64, &Kt[buf][kd1]);
    lds16(vs0 + j0,              &Vt[buf][kd0]);
    lds16(vs1 + j0,              &Vt[buf][kd1]);
  };

  // read-offset tables (bytes)
  int kby[2][4], vby[2][4];
#pragma unroll
  for (int jm = 0; jm < 2; ++jm)
#pragma unroll
    for (int kt = 0; kt < 4; ++kt)
      kby[jm][kt] = (jm*32 + l31) * 128 + (((2*kt + hi) ^ xr) << 4);
#pragma unroll
  for (int nt = 0; nt < 2; ++nt)
#pragma unroll
    for (int gg = 0; gg < 4; ++gg)
      vby[nt][gg] = (nt*32 + l31) * 128 + (((2*gg + hi) ^ xr) << 4);

  auto compute_tile = [&](int cur) {
    const char* Kb = (const char*)&Kt[cur][0];
    const char* Vb = (const char*)&Vt[cur][0];
    // --- QK^T: S^T[j][i], col i = l31, rows j from reg layout ---
    f32x16 st[2];
    __builtin_amdgcn_s_setprio(1);
#pragma unroll
    for (int jm = 0; jm < 2; ++jm) {
      f32x16 t = zero16();
#pragma unroll
      for (int kt = 0; kt < 4; ++kt) {
        bf16x8 kf = *reinterpret_cast<const bf16x8*>(Kb + kby[jm][kt]);
        t = MFMA32(kf, qf[kt], t);
      }
      st[jm] = t;
    }
    __builtin_amdgcn_s_setprio(0);
    // --- exp2 + cvt_pk pack + permlane32_swap -> PA fragments (in-register) ---
    bf16x8 pa[4];
#pragma unroll
    for (int jm = 0; jm < 2; ++jm) {
      unsigned dw[8];
#pragma unroll
      for (int s = 0; s < 8; ++s) {
        float e0 = __builtin_amdgcn_exp2f(st[jm][2*s]);
        float e1 = __builtin_amdgcn_exp2f(st[jm][2*s + 1]);
        asm("v_cvt_pk_bf16_f32 %0, %1, %2" : "=v"(dw[s]) : "v"(e0), "v"(e1));
      }
#pragma unroll
      for (int kt2 = 0; kt2 < 2; ++kt2) {
        unsigned a0 = dw[4*kt2 + 0], b0 = dw[4*kt2 + 2];
        unsigned a1 = dw[4*kt2 + 1], b1 = dw[4*kt2 + 3];
        // a' = [a.lo | b.lo], b' = [a.hi | b.hi]
        asm volatile("v_permlane32_swap_b32 %0, %1" : "+v"(a0), "+v"(b0));
        asm volatile("v_permlane32_swap_b32 %0, %1" : "+v"(a1), "+v"(b1));
        u32x4 uu; uu[0] = a0; uu[1] = a1; uu[2] = b0; uu[3] = b1;
        pa[jm*2 + kt2] = __builtin_bit_cast(bf16x8, uu);
      }
    }
    // --- PV + rowsum (A = PA, rows i = l31; k = j 16 per tile) ---
    __builtin_amdgcn_s_setprio(1);
#pragma unroll
    for (int gg = 0; gg < 4; ++gg) {
      rsacc = MFMA32(pa[gg], ones, rsacc);
#pragma unroll
      for (int nt = 0; nt < 2; ++nt) {
        bf16x8 vf = *reinterpret_cast<const bf16x8*>(Vb + vby[nt][gg]);
        acc[nt] = MFMA32(pa[gg], vf, acc[nt]);
      }
    }
    __builtin_amdgcn_s_setprio(0);
  };

  // ---- pipelined main loop: 32 j-tiles, last one peeled ----
  stage(0, 0);
  int cur = 0;
  for (int jt = 0; jt < 31; ++jt) {
    stage(cur ^ 1, (jt + 1) << 6);
    asm volatile("s_waitcnt vmcnt(4)" ::: "memory");
    __builtin_amdgcn_sched_barrier(0);
    __builtin_amdgcn_s_barrier();
    __builtin_amdgcn_sched_barrier(0);
    compute_tile(cur);
    asm volatile("s_waitcnt lgkmcnt(0)" ::: "memory");
    __builtin_amdgcn_sched_barrier(0);
    __builtin_amdgcn_s_barrier();
    __builtin_amdgcn_sched_barrier(0);
    cur ^= 1;
  }
  asm volatile("s_waitcnt vmcnt(0)" ::: "memory");
  __builtin_amdgcn_sched_barrier(0);
  __builtin_amdgcn_s_barrier();
  __builtin_amdgcn_sched_barrier(0);
  compute_tile(cur);

  // ---- epilogue: divide by rowsum (row-aligned regs), write out ----
#pragma unroll
  for (int r = 0; r < 16; ++r) {
    float inv = 1.0f / rsacc[r];
    int row = iw + (r & 3) + 8*(r >> 2) + 4*hi;
#pragma unroll
    for (int nt = 0; nt < 2; ++nt) {
      int col = h*64 + nt*32 + l31;
      out[((size_t)b * Nn + row) * 256 + col] = (bf16)(acc[nt][r] * inv);
    }
  }
}

// ---------------- LayerNorm + exact GELU: one wave per 512-col row ----------------
__global__ __launch_bounds__(256) void ln_gelu_k(
    bf16* hg, const float* g, const float* bb) {
  const int row = (blockIdx.x << 2) + (threadIdx.x >> 6);
  const int lane = threadIdx.x & 63;
  bf16* hr = hg + (size_t)row * 512 + lane * 8;
  bf16x8 v = *reinterpret_cast<const bf16x8*>(hr);
  float f[8];
  float s = 0.f, sq = 0.f;
#pragma unroll
  for (int i = 0; i < 8; ++i) { f[i] = (float)v[i]; s += f[i]; sq += f[i]*f[i]; }
#pragma unroll
  for (int m = 1; m < 64; m <<= 1) { s += __shfl_xor(s, m); sq += __shfl_xor(sq, m); }
  float mu = s * (1.f / 512.f);
  float var = sq * (1.f / 512.f) - mu * mu;
  float rsv = rsqrtf(var + 1e-5f);
  f32x4 g0 = *reinterpret_cast<const f32x4*>(&g[lane*8]);
  f32x4 g1 = *reinterpret_cast<const f32x4*>(&g[lane*8 + 4]);
  f32x4 b0 = *reinterpret_cast<const f32x4*>(&bb[lane*8]);
  f32x4 b1 = *reinterpret_cast<const f32x4*>(&bb[lane*8 + 4]);
  bf16x8 o;
#pragma unroll
  for (int i = 0; i < 8; ++i) {
    float gv = (i < 4) ? g0[i] : g1[i-4];
    float bv = (i < 4) ? b0[i] : b1[i-4];
    float xn = (f[i] - mu) * rsv * gv + bv;
    float ge = 0.5f * xn * (1.f + erff(xn * 0.70710678118f));
    o[i] = (bf16)ge;
  }
  *reinterpret_cast<bf16x8*>(hr) = o;
}

extern "C" void kernel_launch(void* const* d_in, const int* in_sizes, int n_in,
                              void* d_out, int out_size, void* d_ws, size_t ws_size,
                              hipStream_t stream) {
  (void)in_sizes; (void)n_in; (void)out_size; (void)ws_size;
  const float* x0   = (const float*)d_in[0];
  const float* x1   = (const float*)d_in[1];
  const float* Wqk  = (const float*)d_in[2];
  const float* bqk  = (const float*)d_in[3];
  const float* Wv   = (const float*)d_in[4];
  const float* bv   = (const float*)d_in[5];
  const float* Wout = (const float*)d_in[6];
  const float* bout = (const float*)d_in[7];
  const float* Wf1  = (const float*)d_in[8];
  const float* bf1  = (const float*)d_in[9];
  const float* ln_g = (const float*)d_in[10];
  const float* ln_b = (const float*)d_in[11];
  const float* Wf2  = (const float*)d_in[12];
  const float* bf2  = (const float*)d_in[13];
  float* y = (float*)d_out;

  bf16* p = (bf16*)d_ws;
  bf16* wqkv_t = p; p += 131072;
  bf16* wout_b = p; p += 98304;
  bf16* wfold_t = p; p += 262144;
  bf16* wf1b_t = p; p += 131072;
  bf16* wf2_t  = p; p += 131072;
  float* bfold = (float*)p; p += 1024;     // 512 f32
  bf16* xb0  = p; p += 2097152;
  bf16* xb1  = p; p += 2097152;
  bf16* qks0 = p; p += 2097152;
  bf16* qks1 = p; p += 2097152;
  bf16* vT0  = p; p += 2097152;
  bf16* vT1  = p; p += 2097152;
  bf16* m0   = p; p += 2097152;
  bf16* m1   = p; p += 2097152;
  bf16* hg0  = p; p += 4194304;
  bf16* hg1  = p; p += 4194304;

  dim3 blk(256);
  prep_k<<<6528, blk, 0, stream>>>(Wqk, Wv, Wout, bout, Wf1, Wf2, x0, x1,
                                   wqkv_t, wout_b, wfold_t, wf1b_t, wf2_t, xb0, xb1);
  // weight fold: Wc = [Wout; bout] @ Wf1b  -> wfold_t cols 256-511, bfold
  gemm_k<6,128,2,0><<<dim3(3, 4, 1), blk, 0, stream>>>(
      wout_b, wout_b, nullptr, nullptr, wf1b_t, bf1,
      wfold_t, wfold_t, bfold, bfold, nullptr, nullptr);
  gemm_k<5,128,2,1><<<dim3(64, 4, 2), blk, 0, stream>>>(
      xb0, xb1, nullptr, nullptr, wqkv_t, bqk,
      qks0, qks1, (float*)vT0, (float*)vT1, bv, bv);
  attn_k<<<dim3(16, 16, 2), blk, 0, stream>>>(qks0, qks1, vT0, vT1, m0, m1);
  gemm_k<3,128,2,1><<<dim3(64, 4, 2), blk, 0, stream>>>(
      xb0, xb1, m0, m1, wfold_t, bfold,
      hg0, hg1, nullptr, nullptr, nullptr, nullptr);
  ln_gelu_k<<<dim3(4096), blk, 0, stream>>>(hg0, ln_g, ln_b);
  gemm_k<4,64,3,1><<<dim3(64, 4, 2), blk, 0, stream>>>(
      hg0, hg1, xb0, xb1, wf2_t, bf2,
      nullptr, nullptr, y, y + 2097152, nullptr, nullptr);
}